// Round 7
// baseline (1002.261 us; speedup 1.0000x reference)
//
#include <hip/hip_runtime.h>

typedef _Float16 f16x8 __attribute__((ext_vector_type(8)));
typedef float f32x4 __attribute__((ext_vector_type(4)));
typedef unsigned short u16x8 __attribute__((ext_vector_type(8)));

constexpr int T = 8192, H = 2048, HS = 4096, P = 1024, E = 8;

// ---- d_out layout (floats): final [T*H] | router_logits [T*E] | aux_loss [1]
constexpr size_t LOGITS_OFF = (size_t)T * H;
constexpr size_t AUX_OFF    = LOGITS_OFF + (size_t)T * E;

// ---- workspace layout (bytes) — aliased buffers keep total ~225 MiB
constexpr size_t OFF_SGW  = 0;
constexpr size_t OFF_SDW  = OFF_SGW  + (size_t)HS * H * 2;
constexpr size_t OFF_GW   = OFF_SDW  + (size_t)H * HS * 2;
constexpr size_t OFF_DW   = OFF_GW   + (size_t)E * P * H * 2;
constexpr size_t OFF_BIG0 = OFF_DW   + (size_t)E * H * P * 2;
constexpr size_t OFF_BIG1 = OFF_BIG0 + (size_t)T * H * 2;      // == T*2*P*2
constexpr size_t OFF_H1   = OFF_BIG1 + (size_t)T * HS * 2;     // == T*2*H*2
constexpr size_t OFF_GALL = OFF_H1   + (size_t)T * H * 2;
constexpr size_t OFF_CNT  = OFF_GALL + (size_t)T * E * 4;
constexpr size_t OFF_IMP  = OFF_CNT  + 256;
constexpr size_t OFF_OFFS = OFF_IMP  + 256;
constexpr size_t OFF_SEL  = OFF_OFFS + 256;
constexpr size_t OFF_SELW = OFF_SEL  + (size_t)T * 2 * 4;
constexpr size_t OFF_POS  = OFF_SELW + (size_t)T * 2 * 4;
constexpr size_t OFF_AID  = OFF_POS  + (size_t)T * 2 * 4;
constexpr size_t OFF_TOK  = OFF_AID  + (size_t)T * 2 * 4;
constexpr size_t OFF_WOF  = OFF_TOK  + (size_t)T * 2 * 4;

__device__ __forceinline__ unsigned short f2h(float f) {
  return __builtin_bit_cast(unsigned short, (_Float16)f);
}
__device__ __forceinline__ float h2f(unsigned short u) {
  return (float)__builtin_bit_cast(_Float16, u);
}
__device__ __forceinline__ void gload16(const void* g, void* l) {
  __builtin_amdgcn_global_load_lds((__attribute__((address_space(1))) void*)g,
                                   (__attribute__((address_space(3))) void*)l, 16, 0, 0);
}

#define BARRIER_M asm volatile("s_barrier" ::: "memory")
#define LGKM0_M  do { asm volatile("s_waitcnt lgkmcnt(0)" ::: "memory"); \
                      __builtin_amdgcn_sched_barrier(0); } while (0)

// -------------------- tiny setup kernels --------------------
__global__ void zero_kernel(int* counts, float* imp) {
  int i = threadIdx.x;
  if (i < E) { counts[i] = 0; imp[i] = 0.f; }
}

// fused convert of the 4 weight tensors into the contiguous f16 region.
__global__ void cvt4_kernel(const float* __restrict__ s0, const float* __restrict__ s1,
                            const float* __restrict__ s2, const float* __restrict__ s3,
                            unsigned short* __restrict__ d) {
  const int i = blockIdx.x * 256 + threadIdx.x;   // float4 index, [0, 12M)
  constexpr int N0 = (HS * H) / 4;
  constexpr int N1 = N0 + (H * HS) / 4;
  constexpr int N2 = N1 + (E * P * H) / 4;
  float4 v;
  if (i < N0)      v = ((const float4*)s0)[i];
  else if (i < N1) v = ((const float4*)s1)[i - N0];
  else if (i < N2) v = ((const float4*)s2)[i - N1];
  else             v = ((const float4*)s3)[i - N2];
  ushort4 o;
  o.x = f2h(v.x); o.y = f2h(v.y); o.z = f2h(v.z); o.w = f2h(v.w);
  ((ushort4*)d)[i] = o;
}

// -------------------- router (rw staged in LDS; also emits x16) --------------------
__global__ void router_kernel(const float* __restrict__ x, const float* __restrict__ rw,
                              float* __restrict__ logits, int* __restrict__ counts,
                              float* __restrict__ impg, int* __restrict__ sel,
                              float* __restrict__ selw, int* __restrict__ posA,
                              unsigned short* __restrict__ x16) {
  __shared__ float sRW[E * H];
  __shared__ float sImp[E];
  __shared__ int sCnt[E], sBase[E];
  __shared__ int sE[16][2], sS[16][2];
  const int tid = threadIdx.x, lane = tid & 63, wid = tid >> 6;
  if (tid < E) { sImp[tid] = 0.f; sCnt[tid] = 0; }
#pragma unroll
  for (int i = 0; i < (E * H / 4) / 256; ++i)
    ((float4*)sRW)[i * 256 + tid] = ((const float4*)rw)[i * 256 + tid];
  __syncthreads();

  for (int i = 0; i < 4; ++i) {
    const int ti = wid * 4 + i;
    const int t = blockIdx.x * 16 + ti;
    float p[E];
#pragma unroll
    for (int e = 0; e < E; ++e) p[e] = 0.f;
    const float4* xr = (const float4*)(x + (size_t)t * H);
#pragma unroll
    for (int q = 0; q < 8; ++q) {
      float4 xv = xr[q * 64 + lane];
      ushort4 xo;
      xo.x = f2h(xv.x); xo.y = f2h(xv.y); xo.z = f2h(xv.z); xo.w = f2h(xv.w);
      ((ushort4*)(x16 + (size_t)t * H))[q * 64 + lane] = xo;
#pragma unroll
      for (int e = 0; e < E; ++e) {
        float4 wv = ((const float4*)sRW)[e * 512 + q * 64 + lane];
        p[e] += xv.x * wv.x + xv.y * wv.y + xv.z * wv.z + xv.w * wv.w;
      }
    }
#pragma unroll
    for (int e = 0; e < E; ++e)
#pragma unroll
      for (int o = 32; o; o >>= 1) p[e] += __shfl_xor(p[e], o);

    if (lane == 0) {
      float mx = p[0];
#pragma unroll
      for (int e = 1; e < E; ++e) mx = fmaxf(mx, p[e]);
      float pe[E], s = 0.f;
#pragma unroll
      for (int e = 0; e < E; ++e) { pe[e] = expf(p[e] - mx); s += pe[e]; }
      float inv = 1.f / s;
      int i1 = 0; float b1 = pe[0];
#pragma unroll
      for (int e = 1; e < E; ++e) if (pe[e] > b1) { b1 = pe[e]; i1 = e; }
      int i2 = -1; float b2 = -1.f;
#pragma unroll
      for (int e = 0; e < E; ++e) if (e != i1 && pe[e] > b2) { b2 = pe[e]; i2 = e; }
#pragma unroll
      for (int e = 0; e < E; ++e) logits[(size_t)t * E + e] = p[e];
#pragma unroll
      for (int e = 0; e < E; ++e) atomicAdd(&sImp[e], pe[e] * inv);
      int s1 = atomicAdd(&sCnt[i1], 1);
      int s2 = atomicAdd(&sCnt[i2], 1);
      sel[t * 2] = i1; sel[t * 2 + 1] = i2;
      selw[t * 2] = b1 * inv; selw[t * 2 + 1] = b2 * inv;
      sE[ti][0] = i1; sE[ti][1] = i2; sS[ti][0] = s1; sS[ti][1] = s2;
    }
  }
  __syncthreads();
  if (tid < E) {
    sBase[tid] = atomicAdd(&counts[tid], sCnt[tid]);
    atomicAdd(&impg[tid], sImp[tid]);
  }
  __syncthreads();
  if (lane == 0) {
    for (int i = 0; i < 4; ++i) {
      int ti = wid * 4 + i, t = blockIdx.x * 16 + ti;
      posA[t * 2]     = sBase[sE[ti][0]] + sS[ti][0];
      posA[t * 2 + 1] = sBase[sE[ti][1]] + sS[ti][1];
    }
  }
}

// -------------------- scan / fill / g (unchanged) --------------------
__global__ void scan_kernel(const int* __restrict__ counts, const float* __restrict__ imp,
                            int* __restrict__ offs, float* __restrict__ aux_out) {
  if (threadIdx.x == 0) {
    int off = 0; float simp = 0.f, sld = 0.f;
    for (int e = 0; e < E; ++e) { offs[e] = off; off += counts[e]; simp += imp[e]; sld += (float)counts[e]; }
    offs[E] = off;
    float aux = 0.f;
    for (int e = 0; e < E; ++e)
      aux += (imp[e] / (simp + 1e-9f)) * ((float)counts[e] / (sld + 1e-9f));
    aux_out[0] = (float)E * aux;
  }
}

__global__ void fill_kernel(const int* __restrict__ sel, const float* __restrict__ selw,
                            const int* __restrict__ posA, const int* __restrict__ offs,
                            int* __restrict__ tok_of, float* __restrict__ w_of,
                            int* __restrict__ aid_of) {
  int idx = blockIdx.x * 256 + threadIdx.x;
  if (idx >= T * 2) return;
  int t = idx >> 1;
  int e = sel[idx];
  int aid = offs[e] + posA[idx];
  tok_of[aid] = t;
  w_of[aid] = selw[idx];
  aid_of[idx] = aid;
}

__global__ void g_kernel(const unsigned short* __restrict__ h1, const float* __restrict__ pgw,
                         float* __restrict__ g_all) {
  const int lane = threadIdx.x & 63, wid = threadIdx.x >> 6;
  const int t = blockIdx.x * 4 + wid;
  float p[E];
#pragma unroll
  for (int e = 0; e < E; ++e) p[e] = 0.f;
#pragma unroll
  for (int i = 0; i < 4; ++i) {
    const int h = (i * 64 + lane) * 8;
    u16x8 hv = *(const u16x8*)(h1 + (size_t)t * H + h);
    float hf[8];
#pragma unroll
    for (int j = 0; j < 8; ++j) hf[j] = h2f(hv[j]);
#pragma unroll
    for (int e = 0; e < E; ++e) {
      const float4* wp = (const float4*)(pgw + (size_t)e * H + h);
      float4 w0 = wp[0], w1 = wp[1];
      p[e] += hf[0] * w0.x + hf[1] * w0.y + hf[2] * w0.z + hf[3] * w0.w +
              hf[4] * w1.x + hf[5] * w1.y + hf[6] * w1.z + hf[7] * w1.w;
    }
  }
#pragma unroll
  for (int e = 0; e < E; ++e)
#pragma unroll
    for (int o = 32; o; o >>= 1) p[e] += __shfl_xor(p[e], o);
  if (lane == 0) {
#pragma unroll
    for (int e = 0; e < E; ++e) g_all[(size_t)t * E + e] = 1.f / (1.f + expf(-p[e]));
  }
}

// ==================== 8-phase 256x256 GEMM (T2+T3+T4+T5) ====================
// C[M,N] = A[M,K] . B[N,K]^T, f16 in/out, BK=64, 8 waves (2M x 4N), 128 KiB LDS.
// Stage slots: P3=B(s0,h0+h1) P4=A(s0,h0)+vmcnt(6) P5=A(s0,h1)
//              P7=B(s1,h0+h1) P8=A(s1,h0+h1)+vmcnt(8)
// FIX vs r6: LDS staging dest is WAVE-UNIFORM (readfirstlane'd) — the HW takes
// the LDS base from M0 (scalar); a lane-divergent dest forces a 64-iter
// compiler waterfall (r6's 6x regression). HW adds lane*16 itself.
template <int MODE>
__global__ __launch_bounds__(512, 2) void gemm8(
    const unsigned short* __restrict__ A, const unsigned short* __restrict__ B,
    unsigned short* __restrict__ Cout, const int* __restrict__ tok_of,
    const float* __restrict__ g_all, const float* __restrict__ w_of,
    const int* __restrict__ offs, int N, int K) {
  __shared__ alignas(128) char sAb[2 * 32768];   // side0 | side1, each 256 rows x 128 B
  __shared__ alignas(128) char sBb[2 * 32768];
  const int tid = threadIdx.x, lane = tid & 63, wid = tid >> 6;
  const int wr = wid >> 2, wc = wid & 3;         // 2M x 4N wave grid
  const int bm = blockIdx.x, bn = blockIdx.y;

  int rowStart = 0, cnt = 1 << 30, e = 0;
  const unsigned short* Bp = B;
  if (MODE >= 2) {
    e = blockIdx.z;
    rowStart = offs[e];
    cnt = offs[e + 1] - rowStart;
    if (bm * 256 >= cnt) return;                 // uniform per block
    Bp = B + (size_t)e * N * K;
  }

  // ---- staging: source per-lane (pre-swizzled), LDS dest wave-uniform.
  // logical byte o = u*8192 + tid*16 = u*8192 + wid*1024 + lane*16
  const int wbase = __builtin_amdgcn_readfirstlane(wid * 1024);
  const char* aS[2][2];
  const char* bS[2][2];
  int ldsO[2];
#pragma unroll
  for (int u = 0; u < 2; ++u) {
    const int o = u * 8192 + tid * 16;           // per-lane logical offset (for SOURCE)
    ldsO[u] = u * 8192 + wbase;                  // wave-uniform DEST base (HW adds lane*16)
    const int rih = o >> 7;                      // row in half (128 B rows)
    const int scol = (o & 127) ^ ((rih & 7) << 4);
#pragma unroll
    for (int h = 0; h < 2; ++h) {
      const int absrow = h * 128 + rih;
      long arow;
      if (MODE <= 1) {
        arow = (long)(bm * 256 + absrow);
      } else if (MODE == 2) {
        int gr = bm * 256 + absrow;
        arow = (gr < cnt) ? (long)tok_of[rowStart + gr] : 0L;
      } else {
        int gr = bm * 256 + absrow;
        arow = (gr < cnt) ? (long)(rowStart + gr) : (long)rowStart;
      }
      aS[h][u] = (const char*)A + arow * (long)K * 2 + scol;
      bS[h][u] = (const char*)Bp + (long)(bn * 256 + absrow) * (long)K * 2 + scol;
    }
  }

#define STAGE_A(t, h) do { char* d_ = sAb + ((t) & 1) * 32768 + (h) * 16384;          \
    const size_t kb_ = (size_t)(t) * 128;                                              \
    gload16(aS[h][0] + kb_, d_ + ldsO[0]); gload16(aS[h][1] + kb_, d_ + ldsO[1]); } while (0)
#define STAGE_B(t, h) do { char* d_ = sBb + ((t) & 1) * 32768 + (h) * 16384;          \
    const size_t kb_ = (size_t)(t) * 128;                                              \
    gload16(bS[h][0] + kb_, d_ + ldsO[0]); gload16(bS[h][1] + kb_, d_ + ldsO[1]); } while (0)

  f32x4 acc[8][4];
#pragma unroll
  for (int a_ = 0; a_ < 8; ++a_)
#pragma unroll
    for (int b_ = 0; b_ < 4; ++b_) acc[a_][b_] = (f32x4){0.f, 0.f, 0.f, 0.f};

  f16x8 aF[4][2], b0F[2][2], b1F[2][2];
  const int c00 = (lane >> 4) * 16;              // fragment col-byte base
  const int l15 = lane & 15;
  const int aRow0 = wr * 128 + l15;              // + mh*64 + mt*16
  const int bRow0 = wc * 64 + l15;               // + nh*32 + ntl*16

#define READ_A(side, mh) do {                                                          \
  _Pragma("unroll") for (int mt = 0; mt < 4; ++mt)                                     \
    _Pragma("unroll") for (int kk = 0; kk < 2; ++kk) {                                 \
      const int r_ = aRow0 + (mh) * 64 + mt * 16;                                      \
      const int c_ = kk * 64 + c00;                                                    \
      aF[mt][kk] = *(const f16x8*)(sAb + (side) * 32768 + r_ * 128 + (c_ ^ ((r_ & 7) << 4))); } } while (0)
#define READ_B(side, nh, arr) do {                                                     \
  _Pragma("unroll") for (int ntl = 0; ntl < 2; ++ntl)                                  \
    _Pragma("unroll") for (int kk = 0; kk < 2; ++kk) {                                 \
      const int r_ = bRow0 + (nh) * 32 + ntl * 16;                                     \
      const int c_ = kk * 64 + c00;                                                    \
      arr[ntl][kk] = *(const f16x8*)(sBb + (side) * 32768 + r_ * 128 + (c_ ^ ((r_ & 7) << 4))); } } while (0)
#define MFMA_Q(mh, nh, arr) do {                                                       \
  __builtin_amdgcn_s_setprio(1);                                                       \
  _Pragma("unroll") for (int mt = 0; mt < 4; ++mt)                                     \
    _Pragma("unroll") for (int ntl = 0; ntl < 2; ++ntl)                                \
      _Pragma("unroll") for (int kk = 0; kk < 2; ++kk)                                 \
        acc[(mh) * 4 + mt][(nh) * 2 + ntl] =                                           \
            __builtin_amdgcn_mfma_f32_16x16x32_f16(aF[mt][kk], arr[ntl][kk],           \
                                                   acc[(mh) * 4 + mt][(nh) * 2 + ntl], 0, 0, 0); \
  __builtin_amdgcn_s_setprio(0); } while (0)

  const int NT = K >> 6, NI = NT >> 1;

  // ---- prologue: tiles 0 and 1 fully staged; force tile 0, leave tile 1 in flight
  STAGE_B(0, 0); STAGE_B(0, 1); STAGE_A(0, 0); STAGE_A(0, 1);
  STAGE_B(1, 0); STAGE_B(1, 1); STAGE_A(1, 0); STAGE_A(1, 1);
  asm volatile("s_waitcnt vmcnt(8)" ::: "memory");
  BARRIER_M;

  for (int i = 0; i < NI; ++i) {
    const int t0 = 2 * i;
    const bool pf = (i + 1 < NI);
    // P1: Q00(side0) — reads A-mh0 + B-nh0
    READ_A(0, 0); READ_B(0, 0, b0F);
    BARRIER_M; LGKM0_M;
    MFMA_Q(0, 0, b0F);
    BARRIER_M;
    // P2: Q01(side0) — reads B-nh1
    READ_B(0, 1, b1F);
    BARRIER_M; LGKM0_M;
    MFMA_Q(0, 1, b1F);
    BARRIER_M;
    // P3: Q10(side0) — reads A-mh1; stage B(side0) both halves for t0+2
    READ_A(0, 1);
    if (pf) { STAGE_B(t0 + 2, 0); STAGE_B(t0 + 2, 1); }
    BARRIER_M; LGKM0_M;
    MFMA_Q(1, 0, b0F);
    BARRIER_M;
    // P4: Q11(side0) — no reads; stage A(side0,h0); vmcnt forces side-1 tile
    if (pf) STAGE_A(t0 + 2, 0);
    BARRIER_M;
    MFMA_Q(1, 1, b1F);
    if (pf) { asm volatile("s_waitcnt vmcnt(6)" ::: "memory"); }
    else    { asm volatile("s_waitcnt vmcnt(0)" ::: "memory"); }
    BARRIER_M;
    // P5: Q00(side1) — reads A-mh0 + B-nh0; stage A(side0,h1)
    READ_A(1, 0); READ_B(1, 0, b0F);
    if (pf) STAGE_A(t0 + 2, 1);
    BARRIER_M; LGKM0_M;
    MFMA_Q(0, 0, b0F);
    BARRIER_M;
    // P6: Q01(side1)
    READ_B(1, 1, b1F);
    BARRIER_M; LGKM0_M;
    MFMA_Q(0, 1, b1F);
    BARRIER_M;
    // P7: Q10(side1) — stage B(side1) both halves for t0+3
    READ_A(1, 1);
    if (pf) { STAGE_B(t0 + 3, 0); STAGE_B(t0 + 3, 1); }
    BARRIER_M; LGKM0_M;
    MFMA_Q(1, 0, b0F);
    BARRIER_M;
    // P8: Q11(side1) — stage A(side1) both halves; vmcnt forces side-0 tile
    if (pf) { STAGE_A(t0 + 3, 0); STAGE_A(t0 + 3, 1); }
    BARRIER_M;
    MFMA_Q(1, 1, b1F);
    if (pf) { asm volatile("s_waitcnt vmcnt(8)" ::: "memory"); }
    BARRIER_M;
  }

#undef STAGE_A
#undef STAGE_B
#undef READ_A
#undef READ_B
#undef MFMA_Q

  // ---- epilogue: row = bm*256 + wr*128 + mt16*16 + (lane>>4)*4 + j ;
  //                col = bn*256 + wc*64 + nt*16 + l15
  const int colBase = bn * 256 + wc * 64 + l15;
#pragma unroll
  for (int mt16 = 0; mt16 < 8; ++mt16) {
#pragma unroll
    for (int j = 0; j < 4; ++j) {
      const int rloc = wr * 128 + mt16 * 16 + (lane >> 4) * 4 + j;
      const int grow = bm * 256 + rloc;
      if (MODE <= 1) {
        const size_t base = (size_t)grow * N;
#pragma unroll
        for (int nt = 0; nt < 4; ++nt) {
          float v = acc[mt16][nt][j];
          if (MODE == 0) v = fmaxf(v, 0.f);
          Cout[base + colBase + nt * 16] = f2h(v);
        }
      } else if (MODE == 2) {
        if (grow < cnt) {
          const int aid = rowStart + grow;
          const float gg = g_all[(size_t)tok_of[aid] * E + e];
          const size_t base = (size_t)aid * N;
#pragma unroll
          for (int nt = 0; nt < 4; ++nt) {
            float v = fmaxf(gg * acc[mt16][nt][j], 0.f);
            Cout[base + colBase + nt * 16] = f2h(v);
          }
        }
      } else {
        if (grow < cnt) {
          const int aid = rowStart + grow;
          const float w = w_of[aid];
          const size_t base = (size_t)aid * N;
#pragma unroll
          for (int nt = 0; nt < 4; ++nt)
            Cout[base + colBase + nt * 16] = f2h(w * acc[mt16][nt][j]);
        }
      }
    }
  }
}

// -------------------- combine: final[t,:] = slot[aid0] + slot[aid1] --------------------
__global__ void combine_kernel(const unsigned short* __restrict__ slot,
                               const int* __restrict__ aid_of, float* __restrict__ out) {
  const int idx = blockIdx.x * 256 + threadIdx.x;
  const int t = idx >> 8;
  const int c8 = (idx & 255) * 8;
  const int a0 = aid_of[t * 2], a1 = aid_of[t * 2 + 1];
  u16x8 v0 = *(const u16x8*)(slot + (size_t)a0 * H + c8);
  u16x8 v1 = *(const u16x8*)(slot + (size_t)a1 * H + c8);
  float4 f0, f1;
  f0.x = h2f(v0[0]) + h2f(v1[0]); f0.y = h2f(v0[1]) + h2f(v1[1]);
  f0.z = h2f(v0[2]) + h2f(v1[2]); f0.w = h2f(v0[3]) + h2f(v1[3]);
  f1.x = h2f(v0[4]) + h2f(v1[4]); f1.y = h2f(v0[5]) + h2f(v1[5]);
  f1.z = h2f(v0[6]) + h2f(v1[6]); f1.w = h2f(v0[7]) + h2f(v1[7]);
  float4* op = (float4*)(out + (size_t)t * H + c8);
  op[0] = f0; op[1] = f1;
}

// -------------------- launch --------------------
extern "C" void kernel_launch(void* const* d_in, const int* in_sizes, int n_in,
                              void* d_out, int out_size, void* d_ws, size_t ws_size,
                              hipStream_t stream) {
  const float* x   = (const float*)d_in[0];
  const float* rw  = (const float*)d_in[1];
  const float* sgw = (const float*)d_in[2];
  const float* sdw = (const float*)d_in[3];
  const float* pgw = (const float*)d_in[4];
  const float* gw  = (const float*)d_in[5];
  const float* dw  = (const float*)d_in[6];
  float* out = (float*)d_out;
  char* wsb = (char*)d_ws;

  unsigned short* sgw16 = (unsigned short*)(wsb + OFF_SGW);
  unsigned short* sdw16 = (unsigned short*)(wsb + OFF_SDW);
  unsigned short* gw16  = (unsigned short*)(wsb + OFF_GW);
  unsigned short* dw16  = (unsigned short*)(wsb + OFF_DW);
  unsigned short* x16   = (unsigned short*)(wsb + OFF_BIG0);  // alias: act
  unsigned short* act   = (unsigned short*)(wsb + OFF_BIG0);
  unsigned short* c1    = (unsigned short*)(wsb + OFF_BIG1);  // alias: slot
  unsigned short* slot  = (unsigned short*)(wsb + OFF_BIG1);
  unsigned short* h1    = (unsigned short*)(wsb + OFF_H1);
  float* gall  = (float*)(wsb + OFF_GALL);
  int*   cnts  = (int*)(wsb + OFF_CNT);
  float* imp   = (float*)(wsb + OFF_IMP);
  int*   offs  = (int*)(wsb + OFF_OFFS);
  int*   sel   = (int*)(wsb + OFF_SEL);
  float* selw  = (float*)(wsb + OFF_SELW);
  int*   posA  = (int*)(wsb + OFF_POS);
  int*   aidof = (int*)(wsb + OFF_AID);
  int*   tokof = (int*)(wsb + OFF_TOK);
  float* wof   = (float*)(wsb + OFF_WOF);

  zero_kernel<<<1, 64, 0, stream>>>(cnts, imp);

  cvt4_kernel<<<(HS * H + H * HS + E * P * H + E * H * P) / 4 / 256, 256, 0, stream>>>(
      sgw, sdw, gw, dw, sgw16);

  router_kernel<<<T / 16, 256, 0, stream>>>(x, rw, out + LOGITS_OFF, cnts, imp, sel, selw, posA, x16);
  scan_kernel<<<1, 64, 0, stream>>>(cnts, imp, offs, out + AUX_OFF);
  fill_kernel<<<(T * 2) / 256, 256, 0, stream>>>(sel, selw, posA, offs, tokof, wof, aidof);

  // G1: [T,HS] = relu(x16 . sgw^T), K=H      (NT=32, NI=16)
  gemm8<0><<<dim3(T / 256, HS / 256), 512, 0, stream>>>(x16, sgw16, c1, nullptr, nullptr, nullptr, nullptr, HS, H);
  // G2: h1[T,H] = c1 . sdw^T, K=HS           (NT=64, NI=32)
  gemm8<1><<<dim3(T / 256, H / 256), 512, 0, stream>>>(c1, sdw16, h1, nullptr, nullptr, nullptr, nullptr, H, HS);
  // g
  g_kernel<<<T / 4, 256, 0, stream>>>(h1, pgw, gall);
  // G3: act[aid,P] = relu(g * (h1_gathered . gw[e]^T)), K=H   (NT=32)
  gemm8<2><<<dim3(T * 2 / 256, P / 256, E), 512, 0, stream>>>(h1, gw16, act, tokof, gall, nullptr, offs, P, H);
  // G4: slot[aid,H] = w * (act . dw[e]^T), K=P                (NT=16)
  gemm8<3><<<dim3(T * 2 / 256, H / 256, E), 512, 0, stream>>>(act, dw16, slot, tokof, nullptr, wof, offs, H, P);

  combine_kernel<<<(T * 256) / 256, 256, 0, stream>>>(slot, aidof, out);
}

// Round 8
// 860.416 us; speedup vs baseline: 1.1649x; 1.1649x over previous
//
#include <hip/hip_runtime.h>

typedef _Float16 f16x8 __attribute__((ext_vector_type(8)));
typedef float f32x4 __attribute__((ext_vector_type(4)));
typedef unsigned short u16x8 __attribute__((ext_vector_type(8)));

constexpr int T = 8192, H = 2048, HS = 4096, P = 1024, E = 8;

// ---- d_out layout (floats): final [T*H] | router_logits [T*E] | aux_loss [1]
constexpr size_t LOGITS_OFF = (size_t)T * H;
constexpr size_t AUX_OFF    = LOGITS_OFF + (size_t)T * E;

// ---- workspace layout (bytes) — aliased buffers keep total ~225 MiB
// BIG0: x16 [T*H f16]   (dead after G1)  -> act  [T*2*P f16] (written G3)
// BIG1: c1  [T*HS f16]  (dead after G2)  -> slot [T*2*H f16] (written G4)
constexpr size_t OFF_SGW  = 0;
constexpr size_t OFF_SDW  = OFF_SGW  + (size_t)HS * H * 2;
constexpr size_t OFF_GW   = OFF_SDW  + (size_t)H * HS * 2;
constexpr size_t OFF_DW   = OFF_GW   + (size_t)E * P * H * 2;
constexpr size_t OFF_BIG0 = OFF_DW   + (size_t)E * H * P * 2;
constexpr size_t OFF_BIG1 = OFF_BIG0 + (size_t)T * H * 2;      // == T*2*P*2
constexpr size_t OFF_H1   = OFF_BIG1 + (size_t)T * HS * 2;     // == T*2*H*2
constexpr size_t OFF_GALL = OFF_H1   + (size_t)T * H * 2;
constexpr size_t OFF_CNT  = OFF_GALL + (size_t)T * E * 4;
constexpr size_t OFF_IMP  = OFF_CNT  + 256;
constexpr size_t OFF_OFFS = OFF_IMP  + 256;
constexpr size_t OFF_SEL  = OFF_OFFS + 256;
constexpr size_t OFF_SELW = OFF_SEL  + (size_t)T * 2 * 4;
constexpr size_t OFF_POS  = OFF_SELW + (size_t)T * 2 * 4;
constexpr size_t OFF_AID  = OFF_POS  + (size_t)T * 2 * 4;
constexpr size_t OFF_TOK  = OFF_AID  + (size_t)T * 2 * 4;
constexpr size_t OFF_WOF  = OFF_TOK  + (size_t)T * 2 * 4;

__device__ __forceinline__ unsigned short f2h(float f) {
  return __builtin_bit_cast(unsigned short, (_Float16)f);
}
__device__ __forceinline__ float h2f(unsigned short u) {
  return (float)__builtin_bit_cast(_Float16, u);
}
__device__ __forceinline__ void gload16(const void* g, void* l) {
  __builtin_amdgcn_global_load_lds((__attribute__((address_space(1))) void*)g,
                                   (__attribute__((address_space(3))) void*)l, 16, 0, 0);
}

// -------------------- fused weight convert (+ zero of cnts/imp) --------------------
// segment sizes in float4 units: sgw 2M | sdw 2M | gw 4M | dw 4M  (total 12M)
__global__ void cvt4_kernel(const float* __restrict__ s0, const float* __restrict__ s1,
                            const float* __restrict__ s2, const float* __restrict__ s3,
                            unsigned short* __restrict__ d,
                            int* __restrict__ counts, float* __restrict__ imp) {
  if (blockIdx.x == 0 && threadIdx.x < E) { counts[threadIdx.x] = 0; imp[threadIdx.x] = 0.f; }
  const int i = blockIdx.x * 256 + threadIdx.x;   // float4 index, [0, 12M)
  constexpr int N0 = (HS * H) / 4;
  constexpr int N1 = N0 + (H * HS) / 4;
  constexpr int N2 = N1 + (E * P * H) / 4;
  float4 v;
  if (i < N0)      v = ((const float4*)s0)[i];
  else if (i < N1) v = ((const float4*)s1)[i - N0];
  else if (i < N2) v = ((const float4*)s2)[i - N1];
  else             v = ((const float4*)s3)[i - N2];
  ushort4 o;
  o.x = f2h(v.x); o.y = f2h(v.y); o.z = f2h(v.z); o.w = f2h(v.w);
  ((ushort4*)d)[i] = o;
}

// -------------------- router (rw staged in LDS; also emits x16) --------------------
__global__ void router_kernel(const float* __restrict__ x, const float* __restrict__ rw,
                              float* __restrict__ logits, int* __restrict__ counts,
                              float* __restrict__ impg, int* __restrict__ sel,
                              float* __restrict__ selw, int* __restrict__ posA,
                              unsigned short* __restrict__ x16) {
  __shared__ float sRW[E * H];        // 64 KiB: whole router weight staged once
  __shared__ float sImp[E];
  __shared__ int sCnt[E], sBase[E];
  __shared__ int sE[16][2], sS[16][2];
  const int tid = threadIdx.x, lane = tid & 63, wid = tid >> 6;
  if (tid < E) { sImp[tid] = 0.f; sCnt[tid] = 0; }
#pragma unroll
  for (int i = 0; i < (E * H / 4) / 256; ++i)
    ((float4*)sRW)[i * 256 + tid] = ((const float4*)rw)[i * 256 + tid];
  __syncthreads();

  for (int i = 0; i < 4; ++i) {
    const int ti = wid * 4 + i;
    const int t = blockIdx.x * 16 + ti;
    float p[E];
#pragma unroll
    for (int e = 0; e < E; ++e) p[e] = 0.f;
    const float4* xr = (const float4*)(x + (size_t)t * H);
#pragma unroll
    for (int q = 0; q < 8; ++q) {
      float4 xv = xr[q * 64 + lane];
      ushort4 xo;
      xo.x = f2h(xv.x); xo.y = f2h(xv.y); xo.z = f2h(xv.z); xo.w = f2h(xv.w);
      ((ushort4*)(x16 + (size_t)t * H))[q * 64 + lane] = xo;
#pragma unroll
      for (int e = 0; e < E; ++e) {
        float4 wv = ((const float4*)sRW)[e * 512 + q * 64 + lane];
        p[e] += xv.x * wv.x + xv.y * wv.y + xv.z * wv.z + xv.w * wv.w;
      }
    }
#pragma unroll
    for (int e = 0; e < E; ++e)
#pragma unroll
      for (int o = 32; o; o >>= 1) p[e] += __shfl_xor(p[e], o);

    if (lane == 0) {
      float mx = p[0];
#pragma unroll
      for (int e = 1; e < E; ++e) mx = fmaxf(mx, p[e]);
      float pe[E], s = 0.f;
#pragma unroll
      for (int e = 0; e < E; ++e) { pe[e] = expf(p[e] - mx); s += pe[e]; }
      float inv = 1.f / s;
      int i1 = 0; float b1 = pe[0];
#pragma unroll
      for (int e = 1; e < E; ++e) if (pe[e] > b1) { b1 = pe[e]; i1 = e; }
      int i2 = -1; float b2 = -1.f;
#pragma unroll
      for (int e = 0; e < E; ++e) if (e != i1 && pe[e] > b2) { b2 = pe[e]; i2 = e; }
#pragma unroll
      for (int e = 0; e < E; ++e) logits[(size_t)t * E + e] = p[e];
#pragma unroll
      for (int e = 0; e < E; ++e) atomicAdd(&sImp[e], pe[e] * inv);
      int s1 = atomicAdd(&sCnt[i1], 1);
      int s2 = atomicAdd(&sCnt[i2], 1);
      sel[t * 2] = i1; sel[t * 2 + 1] = i2;
      selw[t * 2] = b1 * inv; selw[t * 2 + 1] = b2 * inv;
      sE[ti][0] = i1; sE[ti][1] = i2; sS[ti][0] = s1; sS[ti][1] = s2;
    }
  }
  __syncthreads();
  if (tid < E) {
    sBase[tid] = atomicAdd(&counts[tid], sCnt[tid]);
    atomicAdd(&impg[tid], sImp[tid]);
  }
  __syncthreads();
  if (lane == 0) {
    for (int i = 0; i < 4; ++i) {
      int ti = wid * 4 + i, t = blockIdx.x * 16 + ti;
      posA[t * 2]     = sBase[sE[ti][0]] + sS[ti][0];
      posA[t * 2 + 1] = sBase[sE[ti][1]] + sS[ti][1];
    }
  }
}

// -------------------- fill (+ fused scan/aux): assignment-id maps --------------------
// Each thread recomputes the 8-wide prefix locally (counts is tiny & L2-hot).
__global__ void fill_kernel(const int* __restrict__ sel, const float* __restrict__ selw,
                            const int* __restrict__ posA, const int* __restrict__ counts,
                            const float* __restrict__ imp,
                            int* __restrict__ offs, float* __restrict__ aux_out,
                            int* __restrict__ tok_of, float* __restrict__ w_of,
                            int* __restrict__ aid_of) {
  int c[E];
#pragma unroll
  for (int e = 0; e < E; ++e) c[e] = counts[e];
  int pre[E + 1];
  pre[0] = 0;
#pragma unroll
  for (int e = 0; e < E; ++e) pre[e + 1] = pre[e] + c[e];

  const int idx = blockIdx.x * 256 + threadIdx.x;  // 0 .. T*2
  if (blockIdx.x == 0 && threadIdx.x == 0) {
#pragma unroll
    for (int e = 0; e <= E; ++e) offs[e] = pre[e];
    float simp = 0.f, sld = (float)pre[E];
#pragma unroll
    for (int e = 0; e < E; ++e) simp += imp[e];
    float aux = 0.f;
#pragma unroll
    for (int e = 0; e < E; ++e)
      aux += (imp[e] / (simp + 1e-9f)) * ((float)c[e] / (sld + 1e-9f));
    aux_out[0] = (float)E * aux;
  }
  if (idx >= T * 2) return;
  int t = idx >> 1;
  int e = sel[idx];
  int aid = pre[e] + posA[idx];
  tok_of[aid] = t;
  w_of[aid] = selw[idx];
  aid_of[idx] = aid;
}

// -------------------- g kernel: g_all[t,e] = sigmoid(h1 . pg_w[e]) --------------------
__global__ void g_kernel(const unsigned short* __restrict__ h1, const float* __restrict__ pgw,
                         float* __restrict__ g_all) {
  const int lane = threadIdx.x & 63, wid = threadIdx.x >> 6;
  const int t = blockIdx.x * 4 + wid;
  float p[E];
#pragma unroll
  for (int e = 0; e < E; ++e) p[e] = 0.f;
#pragma unroll
  for (int i = 0; i < 4; ++i) {
    const int h = (i * 64 + lane) * 8;
    u16x8 hv = *(const u16x8*)(h1 + (size_t)t * H + h);
    float hf[8];
#pragma unroll
    for (int j = 0; j < 8; ++j) hf[j] = h2f(hv[j]);
#pragma unroll
    for (int e = 0; e < E; ++e) {
      const float4* wp = (const float4*)(pgw + (size_t)e * H + h);
      float4 w0 = wp[0], w1 = wp[1];
      p[e] += hf[0] * w0.x + hf[1] * w0.y + hf[2] * w0.z + hf[3] * w0.w +
              hf[4] * w1.x + hf[5] * w1.y + hf[6] * w1.z + hf[7] * w1.w;
    }
  }
#pragma unroll
  for (int e = 0; e < E; ++e)
#pragma unroll
    for (int o = 32; o; o >>= 1) p[e] += __shfl_xor(p[e], o);
  if (lane == 0) {
#pragma unroll
    for (int e = 0; e < E; ++e) g_all[(size_t)t * E + e] = 1.f / (1.f + expf(-p[e]));
  }
}

// -------------------- the GEMM: C[M,N] = A[M,K] . B[N,K]^T (f16 in, MFMA, f16 out)
// Round-2/5 proven core (128x128 tile, 4 waves, BK=64, T2 swizzle, global_load_lds w=16).
// MODE 0: plain rows, relu; MODE 1: plain; MODE 2: gathered rows, relu(g*v);
// MODE 3: rows=aid, w*v.
template <int MODE>
__global__ __launch_bounds__(256) void gemm_bt(
    const unsigned short* __restrict__ A, const unsigned short* __restrict__ B,
    unsigned short* __restrict__ Cout, const int* __restrict__ tok_of,
    const float* __restrict__ g_all, const float* __restrict__ w_of,
    const int* __restrict__ offs, int N, int K) {
  __shared__ alignas(128) char sA[128 * 64 * 2];
  __shared__ alignas(128) char sB[128 * 64 * 2];
  const int tid = threadIdx.x, lane = tid & 63, wid = tid >> 6;
  const int wr = wid >> 1, wc = wid & 1;
  const int bm = blockIdx.x, bn = blockIdx.y;

  int rowStart = 0, cnt = 1 << 30, e = 0;
  const unsigned short* Bp = B;
  if (MODE >= 2) {
    e = blockIdx.z;
    rowStart = offs[e];
    cnt = offs[e + 1] - rowStart;
    if (bm * 128 >= cnt) return;   // uniform per block: barrier-safe
    Bp = B + (size_t)e * N * K;
  }

  // staging pointers: chunk ci = wid*4+it covers tile bytes [ci*1024, +1024), lane -> +lane*16
  const char* aSrc[4];
  const char* bSrc[4];
  char* dA[4];
  char* dB[4];
#pragma unroll
  for (int it = 0; it < 4; ++it) {
    const int ci = wid * 4 + it;
    const int o = ci * 1024 + lane * 16;
    const int row = o >> 7;                        // 128 B per row (BK=64 f16)
    const int cbs = (o & 127) ^ ((row & 7) << 4);  // pre-swizzled source column
    dA[it] = sA + ci * 1024;
    dB[it] = sB + ci * 1024;
    long arow;
    if (MODE <= 1) {
      arow = (long)(bm * 128 + row);
    } else if (MODE == 2) {
      int grow = bm * 128 + row;
      arow = (grow < cnt) ? (long)tok_of[rowStart + grow] : 0L;
    } else {
      int grow = bm * 128 + row;
      arow = (grow < cnt) ? (long)(rowStart + grow) : (long)rowStart;
    }
    aSrc[it] = (const char*)A + arow * (long)K * 2 + cbs;
    bSrc[it] = (const char*)Bp + (long)(bn * 128 + row) * (long)K * 2 + cbs;
  }

  f32x4 acc[4][4];
#pragma unroll
  for (int a_ = 0; a_ < 4; ++a_)
#pragma unroll
    for (int b_ = 0; b_ < 4; ++b_) acc[a_][b_] = (f32x4){0.f, 0.f, 0.f, 0.f};

  for (int k0 = 0; k0 < K; k0 += 64) {
#pragma unroll
    for (int it = 0; it < 4; ++it) {
      gload16(aSrc[it] + (size_t)k0 * 2, dA[it]);
      gload16(bSrc[it] + (size_t)k0 * 2, dB[it]);
    }
    __syncthreads();
#pragma unroll
    for (int kk = 0; kk < 2; ++kk) {
      f16x8 af[4], bfr[4];
      const int c0 = kk * 64 + (lane >> 4) * 16;
#pragma unroll
      for (int mt = 0; mt < 4; ++mt) {
        const int r = wr * 64 + mt * 16 + (lane & 15);
        af[mt] = *(const f16x8*)(sA + r * 128 + (c0 ^ ((r & 7) << 4)));
      }
#pragma unroll
      for (int nt = 0; nt < 4; ++nt) {
        const int r = wc * 64 + nt * 16 + (lane & 15);
        bfr[nt] = *(const f16x8*)(sB + r * 128 + (c0 ^ ((r & 7) << 4)));
      }
#pragma unroll
      for (int mt = 0; mt < 4; ++mt)
#pragma unroll
        for (int nt = 0; nt < 4; ++nt)
          acc[mt][nt] = __builtin_amdgcn_mfma_f32_16x16x32_f16(af[mt], bfr[nt], acc[mt][nt], 0, 0, 0);
    }
    __syncthreads();
  }

  // epilogue: C row = bm*128 + wr*64 + mt*16 + (lane>>4)*4 + j ; col = bn*128 + wc*64 + nt*16 + (lane&15)
  const int colBase = bn * 128 + wc * 64 + (lane & 15);
#pragma unroll
  for (int mt = 0; mt < 4; ++mt) {
#pragma unroll
    for (int j = 0; j < 4; ++j) {
      const int rloc = wr * 64 + mt * 16 + (lane >> 4) * 4 + j;
      const int grow = bm * 128 + rloc;
      if (MODE <= 1) {
        const size_t base = (size_t)grow * N;
#pragma unroll
        for (int nt = 0; nt < 4; ++nt) {
          float v = acc[mt][nt][j];
          if (MODE == 0) v = fmaxf(v, 0.f);
          Cout[base + colBase + nt * 16] = f2h(v);
        }
      } else if (MODE == 2) {
        if (grow < cnt) {
          const int aid = rowStart + grow;
          const float g = g_all[(size_t)tok_of[aid] * E + e];
          const size_t base = (size_t)aid * N;
#pragma unroll
          for (int nt = 0; nt < 4; ++nt) {
            float v = fmaxf(g * acc[mt][nt][j], 0.f);
            Cout[base + colBase + nt * 16] = f2h(v);
          }
        }
      } else {
        if (grow < cnt) {
          const int aid = rowStart + grow;
          const float w = w_of[aid];
          const size_t base = (size_t)aid * N;
#pragma unroll
          for (int nt = 0; nt < 4; ++nt)
            Cout[base + colBase + nt * 16] = f2h(w * acc[mt][nt][j]);
        }
      }
    }
  }
}

// -------------------- combine: final[t,:] = slot[aid0] + slot[aid1] --------------------
__global__ void combine_kernel(const unsigned short* __restrict__ slot,
                               const int* __restrict__ aid_of, float* __restrict__ out) {
  const int idx = blockIdx.x * 256 + threadIdx.x;
  const int t = idx >> 8;
  const int c8 = (idx & 255) * 8;
  const int a0 = aid_of[t * 2], a1 = aid_of[t * 2 + 1];
  u16x8 v0 = *(const u16x8*)(slot + (size_t)a0 * H + c8);
  u16x8 v1 = *(const u16x8*)(slot + (size_t)a1 * H + c8);
  float4 f0, f1;
  f0.x = h2f(v0[0]) + h2f(v1[0]); f0.y = h2f(v0[1]) + h2f(v1[1]);
  f0.z = h2f(v0[2]) + h2f(v1[2]); f0.w = h2f(v0[3]) + h2f(v1[3]);
  f1.x = h2f(v0[4]) + h2f(v1[4]); f1.y = h2f(v0[5]) + h2f(v1[5]);
  f1.z = h2f(v0[6]) + h2f(v1[6]); f1.w = h2f(v0[7]) + h2f(v1[7]);
  float4* op = (float4*)(out + (size_t)t * H + c8);
  op[0] = f0; op[1] = f1;
}

// -------------------- launch --------------------
extern "C" void kernel_launch(void* const* d_in, const int* in_sizes, int n_in,
                              void* d_out, int out_size, void* d_ws, size_t ws_size,
                              hipStream_t stream) {
  const float* x   = (const float*)d_in[0];
  const float* rw  = (const float*)d_in[1];
  const float* sgw = (const float*)d_in[2];
  const float* sdw = (const float*)d_in[3];
  const float* pgw = (const float*)d_in[4];
  const float* gw  = (const float*)d_in[5];
  const float* dw  = (const float*)d_in[6];
  float* out = (float*)d_out;
  char* wsb = (char*)d_ws;

  unsigned short* sgw16 = (unsigned short*)(wsb + OFF_SGW);
  unsigned short* sdw16 = (unsigned short*)(wsb + OFF_SDW);
  unsigned short* gw16  = (unsigned short*)(wsb + OFF_GW);
  unsigned short* dw16  = (unsigned short*)(wsb + OFF_DW);
  unsigned short* x16   = (unsigned short*)(wsb + OFF_BIG0);  // alias: act
  unsigned short* act   = (unsigned short*)(wsb + OFF_BIG0);
  unsigned short* c1    = (unsigned short*)(wsb + OFF_BIG1);  // alias: slot
  unsigned short* slot  = (unsigned short*)(wsb + OFF_BIG1);
  unsigned short* h1    = (unsigned short*)(wsb + OFF_H1);
  float* gall  = (float*)(wsb + OFF_GALL);
  int*   cnts  = (int*)(wsb + OFF_CNT);
  float* imp   = (float*)(wsb + OFF_IMP);
  int*   offs  = (int*)(wsb + OFF_OFFS);
  int*   sel   = (int*)(wsb + OFF_SEL);
  float* selw  = (float*)(wsb + OFF_SELW);
  int*   posA  = (int*)(wsb + OFF_POS);
  int*   aidof = (int*)(wsb + OFF_AID);
  int*   tokof = (int*)(wsb + OFF_TOK);
  float* wof   = (float*)(wsb + OFF_WOF);

  // fused weight converts (+ zero cnts/imp in block 0): 12M float4 total
  cvt4_kernel<<<(HS * H + H * HS + E * P * H + E * H * P) / 4 / 256, 256, 0, stream>>>(
      sgw, sdw, gw, dw, sgw16, cnts, imp);

  // router also produces x16 (rw staged in LDS)
  router_kernel<<<T / 16, 256, 0, stream>>>(x, rw, out + LOGITS_OFF, cnts, imp, sel, selw, posA, x16);

  // fill (+ fused offs/aux computation)
  fill_kernel<<<(T * 2) / 256, 256, 0, stream>>>(sel, selw, posA, cnts, imp, offs, out + AUX_OFF,
                                                 tokof, wof, aidof);

  // G1: [T,HS] = relu(x16 . sgw^T), K=H
  gemm_bt<0><<<dim3(T / 128, HS / 128), 256, 0, stream>>>(x16, sgw16, c1, nullptr, nullptr, nullptr, nullptr, HS, H);
  // G2: h1[T,H] = c1 . sdw^T, K=HS
  gemm_bt<1><<<dim3(T / 128, H / 128), 256, 0, stream>>>(c1, sdw16, h1, nullptr, nullptr, nullptr, nullptr, H, HS);
  // g
  g_kernel<<<T / 4, 256, 0, stream>>>(h1, pgw, gall);
  // G3: act[aid,P] = relu(g * (h1_gathered . gw[e]^T)), K=H
  gemm_bt<2><<<dim3(T / 128, P / 128, E), 256, 0, stream>>>(h1, gw16, act, tokof, gall, nullptr, offs, P, H);
  // G4: slot[aid,H] = w * (act . dw[e]^T), K=P
  gemm_bt<3><<<dim3(T / 128, H / 128, E), 256, 0, stream>>>(act, dw16, slot, tokof, nullptr, wof, offs, H, P);

  combine_kernel<<<(T * 256) / 256, 256, 0, stream>>>(slot, aidof, out);
}

// Round 9
// 735.979 us; speedup vs baseline: 1.3618x; 1.1691x over previous
//
#include <hip/hip_runtime.h>

typedef _Float16 f16x8 __attribute__((ext_vector_type(8)));
typedef float f32x4 __attribute__((ext_vector_type(4)));
typedef unsigned short u16x8 __attribute__((ext_vector_type(8)));

constexpr int T = 8192, H = 2048, HS = 4096, P = 1024, E = 8;

// ---- d_out layout (floats): final [T*H] | router_logits [T*E] | aux_loss [1]
constexpr size_t LOGITS_OFF = (size_t)T * H;
constexpr size_t AUX_OFF    = LOGITS_OFF + (size_t)T * E;

// ---- workspace layout (bytes) — aliased buffers keep total ~225 MiB
// BIG0: x16 [T*H f16]   (dead after G1)  -> act  [T*2*P f16] (written G3)
// BIG1: c1  [T*HS f16]  (dead after G2)  -> slot [T*2*H f16] (written G4)
constexpr size_t OFF_SGW  = 0;
constexpr size_t OFF_SDW  = OFF_SGW  + (size_t)HS * H * 2;
constexpr size_t OFF_GW   = OFF_SDW  + (size_t)H * HS * 2;
constexpr size_t OFF_DW   = OFF_GW   + (size_t)E * P * H * 2;
constexpr size_t OFF_BIG0 = OFF_DW   + (size_t)E * H * P * 2;
constexpr size_t OFF_BIG1 = OFF_BIG0 + (size_t)T * H * 2;      // == T*2*P*2
constexpr size_t OFF_H1   = OFF_BIG1 + (size_t)T * HS * 2;     // == T*2*H*2
constexpr size_t OFF_GALL = OFF_H1   + (size_t)T * H * 2;
constexpr size_t OFF_CNT  = OFF_GALL + (size_t)T * E * 4;
constexpr size_t OFF_IMP  = OFF_CNT  + 256;
constexpr size_t OFF_OFFS = OFF_IMP  + 256;
constexpr size_t OFF_SEL  = OFF_OFFS + 256;
constexpr size_t OFF_SELW = OFF_SEL  + (size_t)T * 2 * 4;
constexpr size_t OFF_POS  = OFF_SELW + (size_t)T * 2 * 4;
constexpr size_t OFF_AID  = OFF_POS  + (size_t)T * 2 * 4;
constexpr size_t OFF_TOK  = OFF_AID  + (size_t)T * 2 * 4;
constexpr size_t OFF_WOF  = OFF_TOK  + (size_t)T * 2 * 4;

__device__ __forceinline__ unsigned short f2h(float f) {
  return __builtin_bit_cast(unsigned short, (_Float16)f);
}
__device__ __forceinline__ float h2f(unsigned short u) {
  return (float)__builtin_bit_cast(_Float16, u);
}
__device__ __forceinline__ void gload16(const void* g, void* l) {
  __builtin_amdgcn_global_load_lds((__attribute__((address_space(1))) void*)g,
                                   (__attribute__((address_space(3))) void*)l, 16, 0, 0);
}

// -------------------- fused weight convert (+ zero of cnts/imp) --------------------
__global__ void cvt4_kernel(const float* __restrict__ s0, const float* __restrict__ s1,
                            const float* __restrict__ s2, const float* __restrict__ s3,
                            unsigned short* __restrict__ d,
                            int* __restrict__ counts, float* __restrict__ imp) {
  if (blockIdx.x == 0 && threadIdx.x < E) { counts[threadIdx.x] = 0; imp[threadIdx.x] = 0.f; }
  const int i = blockIdx.x * 256 + threadIdx.x;   // float4 index, [0, 12M)
  constexpr int N0 = (HS * H) / 4;
  constexpr int N1 = N0 + (H * HS) / 4;
  constexpr int N2 = N1 + (E * P * H) / 4;
  float4 v;
  if (i < N0)      v = ((const float4*)s0)[i];
  else if (i < N1) v = ((const float4*)s1)[i - N0];
  else if (i < N2) v = ((const float4*)s2)[i - N1];
  else             v = ((const float4*)s3)[i - N2];
  ushort4 o;
  o.x = f2h(v.x); o.y = f2h(v.y); o.z = f2h(v.z); o.w = f2h(v.w);
  ((ushort4*)d)[i] = o;
}

// -------------------- router (rw staged in LDS; also emits x16) --------------------
__global__ void router_kernel(const float* __restrict__ x, const float* __restrict__ rw,
                              float* __restrict__ logits, int* __restrict__ counts,
                              float* __restrict__ impg, int* __restrict__ sel,
                              float* __restrict__ selw, int* __restrict__ posA,
                              unsigned short* __restrict__ x16) {
  __shared__ float sRW[E * H];        // 64 KiB: whole router weight staged once
  __shared__ float sImp[E];
  __shared__ int sCnt[E], sBase[E];
  __shared__ int sE[16][2], sS[16][2];
  const int tid = threadIdx.x, lane = tid & 63, wid = tid >> 6;
  if (tid < E) { sImp[tid] = 0.f; sCnt[tid] = 0; }
#pragma unroll
  for (int i = 0; i < (E * H / 4) / 256; ++i)
    ((float4*)sRW)[i * 256 + tid] = ((const float4*)rw)[i * 256 + tid];
  __syncthreads();

  for (int i = 0; i < 4; ++i) {
    const int ti = wid * 4 + i;
    const int t = blockIdx.x * 16 + ti;
    float p[E];
#pragma unroll
    for (int e = 0; e < E; ++e) p[e] = 0.f;
    const float4* xr = (const float4*)(x + (size_t)t * H);
#pragma unroll
    for (int q = 0; q < 8; ++q) {
      float4 xv = xr[q * 64 + lane];
      ushort4 xo;
      xo.x = f2h(xv.x); xo.y = f2h(xv.y); xo.z = f2h(xv.z); xo.w = f2h(xv.w);
      ((ushort4*)(x16 + (size_t)t * H))[q * 64 + lane] = xo;
#pragma unroll
      for (int e = 0; e < E; ++e) {
        float4 wv = ((const float4*)sRW)[e * 512 + q * 64 + lane];
        p[e] += xv.x * wv.x + xv.y * wv.y + xv.z * wv.z + xv.w * wv.w;
      }
    }
#pragma unroll
    for (int e = 0; e < E; ++e)
#pragma unroll
      for (int o = 32; o; o >>= 1) p[e] += __shfl_xor(p[e], o);

    if (lane == 0) {
      float mx = p[0];
#pragma unroll
      for (int e = 1; e < E; ++e) mx = fmaxf(mx, p[e]);
      float pe[E], s = 0.f;
#pragma unroll
      for (int e = 0; e < E; ++e) { pe[e] = expf(p[e] - mx); s += pe[e]; }
      float inv = 1.f / s;
      int i1 = 0; float b1 = pe[0];
#pragma unroll
      for (int e = 1; e < E; ++e) if (pe[e] > b1) { b1 = pe[e]; i1 = e; }
      int i2 = -1; float b2 = -1.f;
#pragma unroll
      for (int e = 0; e < E; ++e) if (e != i1 && pe[e] > b2) { b2 = pe[e]; i2 = e; }
#pragma unroll
      for (int e = 0; e < E; ++e) logits[(size_t)t * E + e] = p[e];
#pragma unroll
      for (int e = 0; e < E; ++e) atomicAdd(&sImp[e], pe[e] * inv);
      int s1 = atomicAdd(&sCnt[i1], 1);
      int s2 = atomicAdd(&sCnt[i2], 1);
      sel[t * 2] = i1; sel[t * 2 + 1] = i2;
      selw[t * 2] = b1 * inv; selw[t * 2 + 1] = b2 * inv;
      sE[ti][0] = i1; sE[ti][1] = i2; sS[ti][0] = s1; sS[ti][1] = s2;
    }
  }
  __syncthreads();
  if (tid < E) {
    sBase[tid] = atomicAdd(&counts[tid], sCnt[tid]);
    atomicAdd(&impg[tid], sImp[tid]);
  }
  __syncthreads();
  if (lane == 0) {
    for (int i = 0; i < 4; ++i) {
      int ti = wid * 4 + i, t = blockIdx.x * 16 + ti;
      posA[t * 2]     = sBase[sE[ti][0]] + sS[ti][0];
      posA[t * 2 + 1] = sBase[sE[ti][1]] + sS[ti][1];
    }
  }
}

// -------------------- fill (+ fused scan/aux): assignment-id maps --------------------
__global__ void fill_kernel(const int* __restrict__ sel, const float* __restrict__ selw,
                            const int* __restrict__ posA, const int* __restrict__ counts,
                            const float* __restrict__ imp,
                            int* __restrict__ offs, float* __restrict__ aux_out,
                            int* __restrict__ tok_of, float* __restrict__ w_of,
                            int* __restrict__ aid_of) {
  int c[E];
#pragma unroll
  for (int e = 0; e < E; ++e) c[e] = counts[e];
  int pre[E + 1];
  pre[0] = 0;
#pragma unroll
  for (int e = 0; e < E; ++e) pre[e + 1] = pre[e] + c[e];

  const int idx = blockIdx.x * 256 + threadIdx.x;  // 0 .. T*2
  if (blockIdx.x == 0 && threadIdx.x == 0) {
#pragma unroll
    for (int e = 0; e <= E; ++e) offs[e] = pre[e];
    float simp = 0.f, sld = (float)pre[E];
#pragma unroll
    for (int e = 0; e < E; ++e) simp += imp[e];
    float aux = 0.f;
#pragma unroll
    for (int e = 0; e < E; ++e)
      aux += (imp[e] / (simp + 1e-9f)) * ((float)c[e] / (sld + 1e-9f));
    aux_out[0] = (float)E * aux;
  }
  if (idx >= T * 2) return;
  int t = idx >> 1;
  int e = sel[idx];
  int aid = pre[e] + posA[idx];
  tok_of[aid] = t;
  w_of[aid] = selw[idx];
  aid_of[idx] = aid;
}

// -------------------- g kernel: g_all[t,e] = sigmoid(h1 . pg_w[e]) --------------------
__global__ void g_kernel(const unsigned short* __restrict__ h1, const float* __restrict__ pgw,
                         float* __restrict__ g_all) {
  const int lane = threadIdx.x & 63, wid = threadIdx.x >> 6;
  const int t = blockIdx.x * 4 + wid;
  float p[E];
#pragma unroll
  for (int e = 0; e < E; ++e) p[e] = 0.f;
#pragma unroll
  for (int i = 0; i < 4; ++i) {
    const int h = (i * 64 + lane) * 8;
    u16x8 hv = *(const u16x8*)(h1 + (size_t)t * H + h);
    float hf[8];
#pragma unroll
    for (int j = 0; j < 8; ++j) hf[j] = h2f(hv[j]);
#pragma unroll
    for (int e = 0; e < E; ++e) {
      const float4* wp = (const float4*)(pgw + (size_t)e * H + h);
      float4 w0 = wp[0], w1 = wp[1];
      p[e] += hf[0] * w0.x + hf[1] * w0.y + hf[2] * w0.z + hf[3] * w0.w +
              hf[4] * w1.x + hf[5] * w1.y + hf[6] * w1.z + hf[7] * w1.w;
    }
  }
#pragma unroll
  for (int e = 0; e < E; ++e)
#pragma unroll
    for (int o = 32; o; o >>= 1) p[e] += __shfl_xor(p[e], o);
  if (lane == 0) {
#pragma unroll
    for (int e = 0; e < E; ++e) g_all[(size_t)t * E + e] = 1.f / (1.f + expf(-p[e]));
  }
}

// -------------------- the GEMM: C[M,N] = A[M,K] . B[N,K]^T (f16 in, MFMA, f16 out)
// Proven core (128x128 tile, 4 waves, BK=64, T2 swizzle, global_load_lds w=16).
// NEW r9: __launch_bounds__(256,3) for 3 blocks/CU; XCD-slab swizzle for MODE<=1
// (preserves xcd = wg&7 HW round-robin; each XCD works a contiguous 8-bm slab,
//  keeping its concurrent blocks' A-panels L2-resident — fixes r4's wrong T1).
// MODE 0: plain rows, relu; MODE 1: plain; MODE 2: gathered rows, relu(g*v);
// MODE 3: rows=aid, w*v.
template <int MODE>
__global__ __launch_bounds__(256, 3) void gemm_bt(
    const unsigned short* __restrict__ A, const unsigned short* __restrict__ B,
    unsigned short* __restrict__ Cout, const int* __restrict__ tok_of,
    const float* __restrict__ g_all, const float* __restrict__ w_of,
    const int* __restrict__ offs, int N, int K) {
  __shared__ alignas(128) char sA[128 * 64 * 2];
  __shared__ alignas(128) char sB[128 * 64 * 2];
  const int tid = threadIdx.x, lane = tid & 63, wid = tid >> 6;
  const int wr = wid >> 1, wc = wid & 1;

  int bm = blockIdx.x, bn = blockIdx.y;
  int rowStart = 0, cnt = 1 << 30, e = 0;
  const unsigned short* Bp = B;
  if (MODE <= 1) {
    // XCD-slab swizzle: valid when gridDim.x == 64 (G1 & G2: T/128 = 64).
    if (gridDim.x == 64) {
      const int wg = blockIdx.y * 64 + blockIdx.x;
      const int xcd = wg & 7;
      const int idx = wg >> 3;            // 0 .. nwg/8-1
      bm = xcd * 8 + (idx & 7);           // contiguous 8-panel A-slab per XCD
      bn = idx >> 3;                      // sweep N within the slab
    }
  } else {
    e = blockIdx.z;
    rowStart = offs[e];
    cnt = offs[e + 1] - rowStart;
    if (bm * 128 >= cnt) return;   // uniform per block: barrier-safe
    Bp = B + (size_t)e * N * K;
  }

  // staging pointers: chunk ci = wid*4+it covers tile bytes [ci*1024, +1024), lane -> +lane*16
  const char* aSrc[4];
  const char* bSrc[4];
  char* dA[4];
  char* dB[4];
#pragma unroll
  for (int it = 0; it < 4; ++it) {
    const int ci = wid * 4 + it;
    const int o = ci * 1024 + lane * 16;
    const int row = o >> 7;                        // 128 B per row (BK=64 f16)
    const int cbs = (o & 127) ^ ((row & 7) << 4);  // pre-swizzled source column
    dA[it] = sA + ci * 1024;
    dB[it] = sB + ci * 1024;
    long arow;
    if (MODE <= 1) {
      arow = (long)(bm * 128 + row);
    } else if (MODE == 2) {
      int grow = bm * 128 + row;
      arow = (grow < cnt) ? (long)tok_of[rowStart + grow] : 0L;
    } else {
      int grow = bm * 128 + row;
      arow = (grow < cnt) ? (long)(rowStart + grow) : (long)rowStart;
    }
    aSrc[it] = (const char*)A + arow * (long)K * 2 + cbs;
    bSrc[it] = (const char*)Bp + (long)(bn * 128 + row) * (long)K * 2 + cbs;
  }

  f32x4 acc[4][4];
#pragma unroll
  for (int a_ = 0; a_ < 4; ++a_)
#pragma unroll
    for (int b_ = 0; b_ < 4; ++b_) acc[a_][b_] = (f32x4){0.f, 0.f, 0.f, 0.f};

  for (int k0 = 0; k0 < K; k0 += 64) {
#pragma unroll
    for (int it = 0; it < 4; ++it) {
      gload16(aSrc[it] + (size_t)k0 * 2, dA[it]);
      gload16(bSrc[it] + (size_t)k0 * 2, dB[it]);
    }
    __syncthreads();
#pragma unroll
    for (int kk = 0; kk < 2; ++kk) {
      f16x8 af[4], bfr[4];
      const int c0 = kk * 64 + (lane >> 4) * 16;
#pragma unroll
      for (int mt = 0; mt < 4; ++mt) {
        const int r = wr * 64 + mt * 16 + (lane & 15);
        af[mt] = *(const f16x8*)(sA + r * 128 + (c0 ^ ((r & 7) << 4)));
      }
#pragma unroll
      for (int nt = 0; nt < 4; ++nt) {
        const int r = wc * 64 + nt * 16 + (lane & 15);
        bfr[nt] = *(const f16x8*)(sB + r * 128 + (c0 ^ ((r & 7) << 4)));
      }
#pragma unroll
      for (int mt = 0; mt < 4; ++mt)
#pragma unroll
        for (int nt = 0; nt < 4; ++nt)
          acc[mt][nt] = __builtin_amdgcn_mfma_f32_16x16x32_f16(af[mt], bfr[nt], acc[mt][nt], 0, 0, 0);
    }
    __syncthreads();
  }

  // epilogue: C row = bm*128 + wr*64 + mt*16 + (lane>>4)*4 + j ; col = bn*128 + wc*64 + nt*16 + (lane&15)
  const int colBase = bn * 128 + wc * 64 + (lane & 15);
#pragma unroll
  for (int mt = 0; mt < 4; ++mt) {
#pragma unroll
    for (int j = 0; j < 4; ++j) {
      const int rloc = wr * 64 + mt * 16 + (lane >> 4) * 4 + j;
      const int grow = bm * 128 + rloc;
      if (MODE <= 1) {
        const size_t base = (size_t)grow * N;
#pragma unroll
        for (int nt = 0; nt < 4; ++nt) {
          float v = acc[mt][nt][j];
          if (MODE == 0) v = fmaxf(v, 0.f);
          Cout[base + colBase + nt * 16] = f2h(v);
        }
      } else if (MODE == 2) {
        if (grow < cnt) {
          const int aid = rowStart + grow;
          const float g = g_all[(size_t)tok_of[aid] * E + e];
          const size_t base = (size_t)aid * N;
#pragma unroll
          for (int nt = 0; nt < 4; ++nt) {
            float v = fmaxf(g * acc[mt][nt][j], 0.f);
            Cout[base + colBase + nt * 16] = f2h(v);
          }
        }
      } else {
        if (grow < cnt) {
          const int aid = rowStart + grow;
          const float w = w_of[aid];
          const size_t base = (size_t)aid * N;
#pragma unroll
          for (int nt = 0; nt < 4; ++nt)
            Cout[base + colBase + nt * 16] = f2h(w * acc[mt][nt][j]);
        }
      }
    }
  }
}

// -------------------- combine: final[t,:] = slot[aid0] + slot[aid1] --------------------
__global__ void combine_kernel(const unsigned short* __restrict__ slot,
                               const int* __restrict__ aid_of, float* __restrict__ out) {
  const int idx = blockIdx.x * 256 + threadIdx.x;
  const int t = idx >> 8;
  const int c8 = (idx & 255) * 8;
  const int a0 = aid_of[t * 2], a1 = aid_of[t * 2 + 1];
  u16x8 v0 = *(const u16x8*)(slot + (size_t)a0 * H + c8);
  u16x8 v1 = *(const u16x8*)(slot + (size_t)a1 * H + c8);
  float4 f0, f1;
  f0.x = h2f(v0[0]) + h2f(v1[0]); f0.y = h2f(v0[1]) + h2f(v1[1]);
  f0.z = h2f(v0[2]) + h2f(v1[2]); f0.w = h2f(v0[3]) + h2f(v1[3]);
  f1.x = h2f(v0[4]) + h2f(v1[4]); f1.y = h2f(v0[5]) + h2f(v1[5]);
  f1.z = h2f(v0[6]) + h2f(v1[6]); f1.w = h2f(v0[7]) + h2f(v1[7]);
  float4* op = (float4*)(out + (size_t)t * H + c8);
  op[0] = f0; op[1] = f1;
}

// -------------------- launch --------------------
extern "C" void kernel_launch(void* const* d_in, const int* in_sizes, int n_in,
                              void* d_out, int out_size, void* d_ws, size_t ws_size,
                              hipStream_t stream) {
  const float* x   = (const float*)d_in[0];
  const float* rw  = (const float*)d_in[1];
  const float* sgw = (const float*)d_in[2];
  const float* sdw = (const float*)d_in[3];
  const float* pgw = (const float*)d_in[4];
  const float* gw  = (const float*)d_in[5];
  const float* dw  = (const float*)d_in[6];
  float* out = (float*)d_out;
  char* wsb = (char*)d_ws;

  unsigned short* sgw16 = (unsigned short*)(wsb + OFF_SGW);
  unsigned short* sdw16 = (unsigned short*)(wsb + OFF_SDW);
  unsigned short* gw16  = (unsigned short*)(wsb + OFF_GW);
  unsigned short* dw16  = (unsigned short*)(wsb + OFF_DW);
  unsigned short* x16   = (unsigned short*)(wsb + OFF_BIG0);  // alias: act
  unsigned short* act   = (unsigned short*)(wsb + OFF_BIG0);
  unsigned short* c1    = (unsigned short*)(wsb + OFF_BIG1);  // alias: slot
  unsigned short* slot  = (unsigned short*)(wsb + OFF_BIG1);
  unsigned short* h1    = (unsigned short*)(wsb + OFF_H1);
  float* gall  = (float*)(wsb + OFF_GALL);
  int*   cnts  = (int*)(wsb + OFF_CNT);
  float* imp   = (float*)(wsb + OFF_IMP);
  int*   offs  = (int*)(wsb + OFF_OFFS);
  int*   sel   = (int*)(wsb + OFF_SEL);
  float* selw  = (float*)(wsb + OFF_SELW);
  int*   posA  = (int*)(wsb + OFF_POS);
  int*   aidof = (int*)(wsb + OFF_AID);
  int*   tokof = (int*)(wsb + OFF_TOK);
  float* wof   = (float*)(wsb + OFF_WOF);

  // fused weight converts (+ zero cnts/imp in block 0): 12M float4 total
  cvt4_kernel<<<(HS * H + H * HS + E * P * H + E * H * P) / 4 / 256, 256, 0, stream>>>(
      sgw, sdw, gw, dw, sgw16, cnts, imp);

  // router also produces x16 (rw staged in LDS)
  router_kernel<<<T / 16, 256, 0, stream>>>(x, rw, out + LOGITS_OFF, cnts, imp, sel, selw, posA, x16);

  // fill (+ fused offs/aux computation)
  fill_kernel<<<(T * 2) / 256, 256, 0, stream>>>(sel, selw, posA, cnts, imp, offs, out + AUX_OFF,
                                                 tokof, wof, aidof);

  // G1: [T,HS] = relu(x16 . sgw^T), K=H
  gemm_bt<0><<<dim3(T / 128, HS / 128), 256, 0, stream>>>(x16, sgw16, c1, nullptr, nullptr, nullptr, nullptr, HS, H);
  // G2: h1[T,H] = c1 . sdw^T, K=HS
  gemm_bt<1><<<dim3(T / 128, H / 128), 256, 0, stream>>>(c1, sdw16, h1, nullptr, nullptr, nullptr, nullptr, H, HS);
  // g
  g_kernel<<<T / 4, 256, 0, stream>>>(h1, pgw, gall);
  // G3: act[aid,P] = relu(g * (h1_gathered . gw[e]^T)), K=H
  gemm_bt<2><<<dim3(T / 128, P / 128, E), 256, 0, stream>>>(h1, gw16, act, tokof, gall, nullptr, offs, P, H);
  // G4: slot[aid,H] = w * (act . dw[e]^T), K=P
  gemm_bt<3><<<dim3(T / 128, H / 128, E), 256, 0, stream>>>(act, dw16, slot, tokof, nullptr, wof, offs, H, P);

  combine_kernel<<<(T * 256) / 256, 256, 0, stream>>>(slot, aidof, out);
}